// Round 4
// baseline (819.972 us; speedup 1.0000x reference)
//
#include <hip/hip_runtime.h>
#include <hip/hip_bf16.h>
#include <cstddef>
#include <cstdint>

#define BB   32
#define TT   2048
#define DIN  512
#define DD   512
#define NN   3072
#define PROJW 4096   // f16 gate row: col = d*8 + k; k=0..5 used (a0,a1,t2,a3,a4,z5)
#define PF   8       // scan prefetch depth (steps)
#define SCANBLKS 64  // scan blocks at the FRONT of the fused grid

typedef __attribute__((ext_vector_type(4))) float f32x4;
typedef __attribute__((ext_vector_type(8))) short s16x8;
typedef _Float16 f16x8 __attribute__((ext_vector_type(8)));

// ---------------------------------------------------------------------------
// helpers
// ---------------------------------------------------------------------------
__device__ __forceinline__ void gl2lds16(const void* g, void* l) {
    __builtin_amdgcn_global_load_lds(
        (const __attribute__((address_space(1))) unsigned*)g,
        (__attribute__((address_space(3))) unsigned*)l, 16, 0, 0);
}

__device__ __forceinline__ unsigned short bfr(float f) {   // f32 -> bf16 RNE
    unsigned u = __float_as_uint(f);
    u += 0x7fffu + ((u >> 16) & 1u);
    return (unsigned short)(u >> 16);
}

__device__ __forceinline__ float ftanh(float x) {
    return 1.f - 2.f * __builtin_amdgcn_rcpf(1.f + __builtin_amdgcn_exp2f(x * 2.885390082f));
}

// ---------------------------------------------------------------------------
// convert x [B][T][DIN] f32 -> x2 [(t*32+b)][DIN] bf16
// ---------------------------------------------------------------------------
__global__ __launch_bounds__(256) void convert_x(
    const float* __restrict__ x, unsigned short* __restrict__ x2)
{
    const int total4 = BB * TT * DIN / 4;
    for (int idx = blockIdx.x * 256 + threadIdx.x; idx < total4;
         idx += gridDim.x * 256) {
        int e = idx * 4;
        int b = e >> 20;
        int t = (e >> 9) & 2047;
        int i = e & 511;
        float4 v = *(const float4*)(x + (size_t)e);
        ushort4 o;
        o.x = bfr(v.x); o.y = bfr(v.y); o.z = bfr(v.z); o.w = bfr(v.w);
        *(ushort4*)(x2 + ((size_t)((t << 5) | b) << 9) + i) = o;
    }
}

// ---------------------------------------------------------------------------
// convert W: W2 row c = gate-interleaved col c = d*6+k -> original row k*512+d
// ---------------------------------------------------------------------------
__global__ __launch_bounds__(128) void convert_w(
    const float* __restrict__ W, const float* __restrict__ bias,
    unsigned short* __restrict__ W2, float* __restrict__ bias2)
{
    int c = blockIdx.x;            // 0..3071, = d*6+k
    int d = c / 6, k = c - d * 6;
    int o = (k << 9) + d;
    const float* src = W + (size_t)o * DIN;
    unsigned short* dst = W2 + (size_t)c * DIN;
    int i = threadIdx.x * 4;
    float4 v = *(const float4*)(src + i);
    ushort4 u;
    u.x = bfr(v.x); u.y = bfr(v.y); u.z = bfr(v.z); u.w = bfr(v.w);
    *(ushort4*)(dst + i) = u;
    if (threadIdx.x == 0) bias2[c] = bias[o];
}

// ---------------------------------------------------------------------------
// Fused per-chunk kernel.
//   blocks [0, SCANBLKS)          : scan of chunk t-1 (projSrc), if t0s >= 0
//   blocks [SCANBLKS, SCANBLKS+nG): 2-phase dbuf MFMA GEMM of chunk t -> projDst
// Scan blocks dispatch first so they overlap the GEMM instead of trailing it.
// ---------------------------------------------------------------------------
__global__ __launch_bounds__(256) void fused_chunk(
    const unsigned short* __restrict__ x2,    // [T*32][512] bf16
    const unsigned short* __restrict__ W2,    // [3072][512] bf16 (permuted)
    const float* __restrict__ bias2,          // [3072] (permuted)
    _Float16* __restrict__ projDst,           // [Tcg*32][PROJW]
    const _Float16* __restrict__ projSrc,     // [Tcs*32][PROJW]
    const float* __restrict__ h0, const float* __restrict__ s0,
    float* __restrict__ outH, float* __restrict__ outS,
    int t0g, int Tcg, int t0s, int Tcs)
{
    __shared__ unsigned short As[2][128][64];
    __shared__ unsigned short Bs[2][128][64];

    if (blockIdx.x < SCANBLKS) {
        // ------------------------- scan of chunk t-1 -------------------------
        if (t0s < 0) return;
        const int gid = blockIdx.x * 256 + threadIdx.x;   // 0..16383
        const int b   = gid >> 9;
        const int d   = gid & 511;

        float h, s;
        if (t0s == 0) { h = h0[gid]; s = s0[gid]; }
        else {
            h = outH[((size_t)b * TT + (t0s - 1)) * DD + d];
            s = outS[gid];
        }

        const f16x8* pbase = (const f16x8*)(projSrc + (size_t)b * PROJW + d * 8);
        const size_t tstride = ((size_t)BB * PROJW) / 8;
        float* oH = outH + ((size_t)b * TT + t0s) * DD + d;

        f16x8 bufA[PF], bufB[PF];
        #pragma unroll
        for (int u = 0; u < PF; ++u) bufA[u] = pbase[(size_t)u * tstride];

        for (int tb = 0; tb < Tcs; tb += 2 * PF) {
            #pragma unroll
            for (int u = 0; u < PF; ++u) {
                int t = tb + PF + u; if (t > Tcs - 1) t = Tcs - 1;
                bufB[u] = pbase[(size_t)t * tstride];
            }
            #pragma unroll
            for (int u = 0; u < PF; ++u) {
                f16x8 g = bufA[u];
                float a0 = (float)g[0], a1 = (float)g[1], t2 = (float)g[2];
                float a3 = (float)g[3], a4 = (float)g[4], z5 = (float)g[5];
                s = __builtin_fmaf(a0, s, a1 * t2);
                h = __builtin_fmaf(a3, h, a4 * ftanh(z5 + s));
                oH[(size_t)(tb + u) * DD] = h;
            }
            #pragma unroll
            for (int u = 0; u < PF; ++u) {
                int t = tb + 2 * PF + u; if (t > Tcs - 1) t = Tcs - 1;
                bufA[u] = pbase[(size_t)t * tstride];
            }
            #pragma unroll
            for (int u = 0; u < PF; ++u) {
                f16x8 g = bufB[u];
                float a0 = (float)g[0], a1 = (float)g[1], t2 = (float)g[2];
                float a3 = (float)g[3], a4 = (float)g[4], z5 = (float)g[5];
                s = __builtin_fmaf(a0, s, a1 * t2);
                h = __builtin_fmaf(a3, h, a4 * ftanh(z5 + s));
                oH[(size_t)(tb + PF + u) * DD] = h;
            }
        }
        outS[gid] = s;
        return;
    }

    // --------------------------- GEMM of chunk t ----------------------------
    if (t0g < 0) return;
    const int f    = blockIdx.x - SCANBLKS;
    const int nwgx = NN / 128;                // 24 col-tiles
    const int bx   = f % nwgx;
    const int by   = f / nwgx;

    const int tid  = threadIdx.x;
    const int lane = tid & 63;
    const int w    = tid >> 6;
    const int wr   = w >> 1, wc = w & 1;
    const int lr   = lane & 15, lq = lane >> 4;

    const int row0 = by * 128;
    const int col0 = bx * 128;
    const size_t growA = (size_t)t0g * BB + row0;

    f32x4 acc[4][4] = {};

    auto stage = [&](int buf, int k0) {
        #pragma unroll
        for (int i = 0; i < 4; ++i) {
            int c  = tid + i * 256;           // 16B chunk id
            int r  = c >> 3;
            int kc = (c & 7) * 8;
            gl2lds16(x2 + (growA + r) * DIN + k0 + kc, &As[buf][r][kc]);
            gl2lds16(W2 + (size_t)(col0 + r) * DIN + k0 + kc, &Bs[buf][r][kc]);
        }
    };

    stage(0, 0);
    __syncthreads();                          // vmcnt(0) drain: buf0 ready

    int cur = 0;
    #pragma unroll
    for (int k0 = 0; k0 < DIN; k0 += 64) {
        if (k0 + 64 < DIN) stage(cur ^ 1, k0 + 64);   // overlap next stage
        #pragma unroll
        for (int kk = 0; kk < 64; kk += 32) {
            s16x8 av[4], bv[4];
            #pragma unroll
            for (int i = 0; i < 4; ++i)
                av[i] = *(const s16x8*)&As[cur][wr * 64 + i * 16 + lr][kk + lq * 8];
            #pragma unroll
            for (int j = 0; j < 4; ++j)
                bv[j] = *(const s16x8*)&Bs[cur][wc * 64 + j * 16 + lr][kk + lq * 8];
            #pragma unroll
            for (int i = 0; i < 4; ++i)
                #pragma unroll
                for (int j = 0; j < 4; ++j)
                    acc[i][j] = __builtin_amdgcn_mfma_f32_16x16x32_bf16(
                        av[i], bv[j], acc[i][j], 0, 0, 0);
        }
        __syncthreads();   // drains vmcnt(0): next buf staged; lgkm: reads done
        cur ^= 1;
    }

    // Epilogue: bias + per-gate activation + f16 store (gate-interleaved)
    #pragma unroll
    for (int j = 0; j < 4; ++j) {
        int col  = col0 + wc * 64 + j * 16 + lr;          // 0..3071 = d*6+k
        int dcol = (int)(((unsigned)col * 43691u) >> 18); // col/6 exact
        int k    = col - 6 * dcol;
        int scol = (dcol << 3) + k;                       // d*8+k
        float bc = bias2[col];
        const bool  isT = (k == 2);
        const bool  isI = (k == 5);
        const float m   = isT ? 2.885390082f : -1.442695041f;
        #pragma unroll
        for (int i = 0; i < 4; ++i) {
            int rbase = row0 + wr * 64 + i * 16 + lq * 4;
            #pragma unroll
            for (int r = 0; r < 4; ++r) {
                float z  = acc[i][j][r] + bc;
                float e  = __builtin_amdgcn_exp2f(z * m);
                float rr = __builtin_amdgcn_rcpf(1.f + e);
                float v  = isT ? (1.f - 2.f * rr) : rr;
                if (isI) v = z;
                projDst[(size_t)(rbase + r) * PROJW + scol] = (_Float16)v;
            }
        }
    }
}

// ---------------------------------------------------------------------------
extern "C" void kernel_launch(void* const* d_in, const int* in_sizes, int n_in,
                              void* d_out, int out_size, void* d_ws, size_t ws_size,
                              hipStream_t stream) {
    const float* x    = (const float*)d_in[0];
    const float* h0   = (const float*)d_in[1];
    const float* s0   = (const float*)d_in[2];
    const float* W    = (const float*)d_in[3];
    const float* bias = (const float*)d_in[4];

    float* outH = (float*)d_out;
    float* outS = outH + (size_t)BB * TT * DD;

    char* ws = (char*)d_ws;
    const size_t x2_bytes = (size_t)BB * TT * DIN * 2;       // 64 MB
    const size_t w2_bytes = (size_t)NN * DIN * 2;            // 3 MB
    const size_t b2_bytes = (size_t)NN * 4;
    unsigned short* x2    = (unsigned short*)ws;
    unsigned short* W2    = (unsigned short*)(ws + x2_bytes);
    float*          bias2 = (float*)(ws + x2_bytes + w2_bytes);

    const size_t fixed = x2_bytes + w2_bytes + b2_bytes;
    const size_t per_t = (size_t)BB * PROJW * 2;             // 256 KB / step
    size_t avail = ws_size > fixed ? ws_size - fixed : 0;
    int TcMax = (int)(avail / (2 * per_t));                  // double-buffered
    if (TcMax > 512) TcMax = 512;
    TcMax &= ~15;
    if (TcMax < 16) TcMax = 16;

    _Float16* projA = (_Float16*)(ws + fixed);
    _Float16* projB = projA + (size_t)TcMax * BB * PROJW;

    convert_x<<<2048, 256, 0, stream>>>(x, x2);
    convert_w<<<NN, 128, 0, stream>>>(W, bias, W2, bias2);

    const int nC = (TT + TcMax - 1) / TcMax;
    int prevT0 = -1, prevTc = 0;
    const _Float16* prevProj = nullptr;

    for (int ci = 0; ci <= nC; ++ci) {
        const bool hasG = (ci < nC);
        int t0 = ci * TcMax;
        int Tc = 0;
        _Float16* dst = nullptr;
        int nG = 0;
        if (hasG) {
            Tc  = TT - t0; if (Tc > TcMax) Tc = TcMax;
            dst = (ci & 1) ? projB : projA;
            nG  = (NN / 128) * (Tc * BB / 128);
        }
        fused_chunk<<<dim3(SCANBLKS + nG), 256, 0, stream>>>(
            x2, W2, bias2, dst, prevProj, h0, s0, outH, outS,
            hasG ? t0 : -1, Tc, prevT0, prevTc);
        if (hasG) { prevProj = dst; prevT0 = t0; prevTc = Tc; }
    }
}

// Round 5
// 713.678 us; speedup vs baseline: 1.1489x; 1.1489x over previous
//
#include <hip/hip_runtime.h>
#include <hip/hip_bf16.h>
#include <cstddef>
#include <cstdint>

#define BB   32
#define TT   2048
#define DIN  512
#define DD   512
#define NN   3072
#define PROJW 4096   // f16 gate row: col = d*8 + k; k=0..5 used (a0,a1,t2,a3,a4,z5)
#define PF   16      // scan prefetch depth (steps)

#define BMT 256      // GEMM tile M
#define BNT 256      // GEMM tile N
#define BKT 64       // GEMM K-tile
#define NKT (DIN / BKT)   // 8 K-tiles

typedef __attribute__((ext_vector_type(4))) float f32x4;
typedef __attribute__((ext_vector_type(8))) short s16x8;
typedef _Float16 f16x8 __attribute__((ext_vector_type(8)));

// ---------------------------------------------------------------------------
// helpers
// ---------------------------------------------------------------------------
__device__ __forceinline__ void gl2lds16(const void* g, void* l) {
    __builtin_amdgcn_global_load_lds(
        (const __attribute__((address_space(1))) unsigned*)g,
        (__attribute__((address_space(3))) unsigned*)l, 16, 0, 0);
}

__device__ __forceinline__ unsigned short bfr(float f) {   // f32 -> bf16 RNE
    unsigned u = __float_as_uint(f);
    u += 0x7fffu + ((u >> 16) & 1u);
    return (unsigned short)(u >> 16);
}

__device__ __forceinline__ float ftanh(float x) {
    return 1.f - 2.f * __builtin_amdgcn_rcpf(1.f + __builtin_amdgcn_exp2f(x * 2.885390082f));
}

// ---------------------------------------------------------------------------
// convert x [B][T][DIN] f32 -> x2 [(t*32+b)][DIN] bf16
// ---------------------------------------------------------------------------
__global__ __launch_bounds__(256) void convert_x(
    const float* __restrict__ x, unsigned short* __restrict__ x2)
{
    const int total4 = BB * TT * DIN / 4;
    for (int idx = blockIdx.x * 256 + threadIdx.x; idx < total4;
         idx += gridDim.x * 256) {
        int e = idx * 4;
        int b = e >> 20;
        int t = (e >> 9) & 2047;
        int i = e & 511;
        float4 v = *(const float4*)(x + (size_t)e);
        ushort4 o;
        o.x = bfr(v.x); o.y = bfr(v.y); o.z = bfr(v.z); o.w = bfr(v.w);
        *(ushort4*)(x2 + ((size_t)((t << 5) | b) << 9) + i) = o;
    }
}

// ---------------------------------------------------------------------------
// convert W: W2 row c = gate-interleaved col c = d*6+k -> original row k*512+d
// ---------------------------------------------------------------------------
__global__ __launch_bounds__(128) void convert_w(
    const float* __restrict__ W, const float* __restrict__ bias,
    unsigned short* __restrict__ W2, float* __restrict__ bias2)
{
    int c = blockIdx.x;            // 0..3071, = d*6+k
    int d = c / 6, k = c - d * 6;
    int o = (k << 9) + d;
    const float* src = W + (size_t)o * DIN;
    unsigned short* dst = W2 + (size_t)c * DIN;
    int i = threadIdx.x * 4;
    float4 v = *(const float4*)(src + i);
    ushort4 u;
    u.x = bfr(v.x); u.y = bfr(v.y); u.z = bfr(v.z); u.w = bfr(v.w);
    *(ushort4*)(dst + i) = u;
    if (threadIdx.x == 0) bias2[c] = bias[o];
}

// ---------------------------------------------------------------------------
// 256x256 8-wave deep-pipelined MFMA GEMM (T2+T3+T4+T5), BK=64, dbuf 128KB.
// LDS layout: A/B tiles [256 rows][64 k] ushort, 16B-chunk XOR swizzle:
//   phys_chunk = logical_chunk ^ (row & 7)  (applied on global src + ds_read)
// Counted vmcnt(8) at K-tile boundaries; per-phase barrier/lgkm/setprio/MFMA.
// Epilogue: bias + gate activation, f16 store at scol = d*8+k.
// ---------------------------------------------------------------------------
__global__ __launch_bounds__(512, 2) void gemm_proj8(
    const unsigned short* __restrict__ x2,    // [T*32][512] bf16
    const unsigned short* __restrict__ W2,    // [3072][512] bf16 (permuted)
    const float* __restrict__ bias2,          // [3072] (permuted)
    _Float16* __restrict__ proj,              // [Mc][PROJW]
    int t0)
{
    __shared__ unsigned short lds[4 * 256 * 64];   // 128 KB: A0,B0,A1,B1
    unsigned short* const A0 = lds;
    unsigned short* const B0 = lds + 16384;
    unsigned short* const A1 = lds + 32768;
    unsigned short* const B1 = lds + 49152;

    const int tid  = threadIdx.x;
    const int bx   = blockIdx.x % (NN / BNT);   // 12 col tiles
    const int by   = blockIdx.x / (NN / BNT);
    const int row0 = by * BMT;
    const int col0 = bx * BNT;
    const size_t growA = (size_t)t0 * BB + row0;

    const int lane = tid & 63;
    const int wv   = tid >> 6;       // 0..7
    const int wm   = wv >> 2;        // 0..1  (M half)
    const int wn   = wv & 3;         // 0..3  (N quarter)
    const int lr   = lane & 15;
    const int lq   = lane >> 4;

    // ---- staging: 8 gl2lds16 per thread per K-tile (A:4, B:4) ----
    auto stage = [&](unsigned short* Ab, unsigned short* Bb, int kt) {
        const int k0 = kt * BKT;
        #pragma unroll
        for (int a = 0; a < 4; ++a) {
            int cid = a * 512 + tid;          // 16B-chunk id, 0..2047
            int rt  = cid >> 3;
            int cp  = cid & 7;
            int cl  = cp ^ (rt & 7);          // inverse-swizzled global source
            gl2lds16(x2 + (growA + rt) * DIN + k0 + cl * 8, Ab + rt * 64 + cp * 8);
        }
        #pragma unroll
        for (int a = 0; a < 4; ++a) {
            int cid = a * 512 + tid;
            int rt  = cid >> 3;
            int cp  = cid & 7;
            int cl  = cp ^ (rt & 7);
            gl2lds16(W2 + (size_t)(col0 + rt) * DIN + k0 + cl * 8, Bb + rt * 64 + cp * 8);
        }
    };

    f32x4 acc[8][4] = {};

    // ---- one phase: quadrant q of the wave's 128x64 output, full K=64 ----
    auto phase = [&](const unsigned short* Ab, const unsigned short* Bb, int q) {
        const int qi = q & 1, qj = q >> 1;
        s16x8 av[4][2], bv[2][2];
        #pragma unroll
        for (int i = 0; i < 4; ++i) {
            int row = wm * 128 + qi * 64 + i * 16 + lr;
            #pragma unroll
            for (int x = 0; x < 2; ++x) {
                int cp = (x * 4 + lq) ^ (row & 7);   // swizzled read
                av[i][x] = *(const s16x8*)(Ab + row * 64 + cp * 8);
            }
        }
        #pragma unroll
        for (int j = 0; j < 2; ++j) {
            int col = wn * 64 + qj * 32 + j * 16 + lr;
            #pragma unroll
            for (int x = 0; x < 2; ++x) {
                int cp = (x * 4 + lq) ^ (col & 7);
                bv[j][x] = *(const s16x8*)(Bb + col * 64 + cp * 8);
            }
        }
        __builtin_amdgcn_s_barrier();
        asm volatile("s_waitcnt lgkmcnt(0)" ::: "memory");
        __builtin_amdgcn_sched_barrier(0);
        __builtin_amdgcn_s_setprio(1);
        #pragma unroll
        for (int i = 0; i < 4; ++i)
            #pragma unroll
            for (int j = 0; j < 2; ++j)
                #pragma unroll
                for (int x = 0; x < 2; ++x)
                    acc[qi * 4 + i][qj * 2 + j] =
                        __builtin_amdgcn_mfma_f32_16x16x32_bf16(
                            av[i][x], bv[j][x], acc[qi * 4 + i][qj * 2 + j], 0, 0, 0);
        __builtin_amdgcn_s_setprio(0);
        __builtin_amdgcn_s_barrier();
    };

    // ---- prologue: stage kt0 + kt1, wait kt0 (kt1 stays in flight) ----
    stage(A0, B0, 0);
    stage(A1, B1, 1);
    asm volatile("s_waitcnt vmcnt(8)" ::: "memory");
    __builtin_amdgcn_s_barrier();

    // ---- main loop ----
    #pragma unroll
    for (int kt = 0; kt < NKT; ++kt) {
        unsigned short* Ab = (kt & 1) ? A1 : A0;
        unsigned short* Bb = (kt & 1) ? B1 : B0;
        #pragma unroll
        for (int q = 0; q < 4; ++q) phase(Ab, Bb, q);
        // boundary: all waves past phase-3 barrier => buf[kt&1] free
        if (kt + 2 < NKT) {
            stage(Ab, Bb, kt + 2);                         // refill current buf
            asm volatile("s_waitcnt vmcnt(8)" ::: "memory"); // kt+1 loads done
        } else if (kt + 1 < NKT) {
            asm volatile("s_waitcnt vmcnt(0)" ::: "memory");
        }
        if (kt + 1 < NKT) __builtin_amdgcn_s_barrier();
    }

    // ---- epilogue: bias + per-gate activation + f16 store ----
    #pragma unroll
    for (int j = 0; j < 4; ++j) {
        int col  = col0 + wn * 64 + j * 16 + lr;          // 0..3071 = d*6+k
        int dcol = (int)(((unsigned)col * 43691u) >> 18); // col/6 exact
        int k    = col - 6 * dcol;
        int scol = (dcol << 3) + k;                       // d*8+k
        float bc = bias2[col];
        const bool  isT = (k == 2);
        const bool  isI = (k == 5);
        const float m   = isT ? 2.885390082f : -1.442695041f;
        #pragma unroll
        for (int i = 0; i < 8; ++i) {
            int rbase = row0 + wm * 128 + i * 16 + lq * 4;
            #pragma unroll
            for (int r = 0; r < 4; ++r) {
                float z  = acc[i][j][r] + bc;
                float e  = __builtin_amdgcn_exp2f(z * m);
                float rr = __builtin_amdgcn_rcpf(1.f + e);
                float v  = isT ? (1.f - 2.f * rr) : rr;
                if (isI) v = z;
                proj[(size_t)(rbase + r) * PROJW + scol] = (_Float16)v;
            }
        }
    }
}

// ---------------------------------------------------------------------------
// Scan: one thread per (b,d), PF=16 register prefetch (Little's law: 2x
// in-flight bytes vs PF=8), one dwordx4 per step. Gates pre-activated.
// ---------------------------------------------------------------------------
__global__ __launch_bounds__(64) void scan_chunk(
    const _Float16* __restrict__ proj,   // [Tc*32][PROJW]
    const float* __restrict__ h0, const float* __restrict__ s0,
    float* __restrict__ outH, float* __restrict__ outS,
    int t0, int Tc)
{
    const int gid = blockIdx.x * 64 + threadIdx.x;   // 0..16383
    const int b   = gid >> 9;
    const int d   = gid & 511;

    float h, s;
    if (t0 == 0) { h = h0[gid]; s = s0[gid]; }
    else {
        h = outH[((size_t)b * TT + (t0 - 1)) * DD + d];
        s = outS[gid];
    }

    const f16x8* pbase = (const f16x8*)(proj + (size_t)b * PROJW + d * 8);
    const size_t tstride = ((size_t)BB * PROJW) / 8;
    float* oH = outH + ((size_t)b * TT + t0) * DD + d;

    f16x8 bufA[PF], bufB[PF];
    #pragma unroll
    for (int u = 0; u < PF; ++u) bufA[u] = pbase[(size_t)u * tstride];

    for (int tb = 0; tb < Tc; tb += 2 * PF) {
        #pragma unroll
        for (int u = 0; u < PF; ++u) {
            int t = tb + PF + u; if (t > Tc - 1) t = Tc - 1;
            bufB[u] = pbase[(size_t)t * tstride];
        }
        #pragma unroll
        for (int u = 0; u < PF; ++u) {
            f16x8 g = bufA[u];
            float a0 = (float)g[0], a1 = (float)g[1], t2 = (float)g[2];
            float a3 = (float)g[3], a4 = (float)g[4], z5 = (float)g[5];
            s = __builtin_fmaf(a0, s, a1 * t2);
            h = __builtin_fmaf(a3, h, a4 * ftanh(z5 + s));
            oH[(size_t)(tb + u) * DD] = h;
        }
        #pragma unroll
        for (int u = 0; u < PF; ++u) {
            int t = tb + 2 * PF + u; if (t > Tc - 1) t = Tc - 1;
            bufA[u] = pbase[(size_t)t * tstride];
        }
        #pragma unroll
        for (int u = 0; u < PF; ++u) {
            f16x8 g = bufB[u];
            float a0 = (float)g[0], a1 = (float)g[1], t2 = (float)g[2];
            float a3 = (float)g[3], a4 = (float)g[4], z5 = (float)g[5];
            s = __builtin_fmaf(a0, s, a1 * t2);
            h = __builtin_fmaf(a3, h, a4 * ftanh(z5 + s));
            oH[(size_t)(tb + PF + u) * DD] = h;
        }
    }

    outS[gid] = s;
}

// ---------------------------------------------------------------------------
extern "C" void kernel_launch(void* const* d_in, const int* in_sizes, int n_in,
                              void* d_out, int out_size, void* d_ws, size_t ws_size,
                              hipStream_t stream) {
    const float* x    = (const float*)d_in[0];
    const float* h0   = (const float*)d_in[1];
    const float* s0   = (const float*)d_in[2];
    const float* W    = (const float*)d_in[3];
    const float* bias = (const float*)d_in[4];

    float* outH = (float*)d_out;
    float* outS = outH + (size_t)BB * TT * DD;

    char* ws = (char*)d_ws;
    const size_t x2_bytes = (size_t)BB * TT * DIN * 2;       // 64 MB
    const size_t w2_bytes = (size_t)NN * DIN * 2;            // 3 MB
    const size_t b2_bytes = (size_t)NN * 4;
    unsigned short* x2    = (unsigned short*)ws;
    unsigned short* W2    = (unsigned short*)(ws + x2_bytes);
    float*          bias2 = (float*)(ws + x2_bytes + w2_bytes);
    _Float16*       proj  = (_Float16*)(ws + x2_bytes + w2_bytes + b2_bytes);

    const size_t fixed = x2_bytes + w2_bytes + b2_bytes;
    const size_t per_t = (size_t)BB * PROJW * 2;             // 256 KB / step
    size_t avail = ws_size > fixed ? ws_size - fixed : 0;
    int TcMax = (int)(avail / per_t);
    if (TcMax > 512) TcMax = 512;   // keep proj chunk L3-resident
    TcMax &= ~31;                   // multiple of 32 (scan 2*PF) and 8 (M tile)
    if (TcMax < 32) TcMax = 32;

    convert_x<<<2048, 256, 0, stream>>>(x, x2);
    convert_w<<<NN, 128, 0, stream>>>(W, bias, W2, bias2);

    for (int t0 = 0; t0 < TT; t0 += TcMax) {
        int Tc = TT - t0;
        if (Tc > TcMax) Tc = TcMax;
        int nblk = (NN / BNT) * (Tc * BB / BMT);
        gemm_proj8<<<nblk, 512, 0, stream>>>(x2, W2, bias2, proj, t0);
        scan_chunk<<<(BB * DD) / 64, 64, 0, stream>>>(proj, h0, s0, outH, outS, t0, Tc);
    }
}

// Round 6
// 486.640 us; speedup vs baseline: 1.6850x; 1.4665x over previous
//
#include <hip/hip_runtime.h>
#include <hip/hip_bf16.h>
#include <cstddef>
#include <cstdint>

#define BB   32
#define TT   2048
#define DIN  512
#define DD   512
#define NN   3072
#define PW   3072    // proj row width (f16): col = p*1024 + d*2 + q, gate k=2p+q
#define PF   16      // scan prefetch depth (steps)

#define BMT 256      // GEMM tile M
#define BNT 256      // GEMM tile N
#define BKT 64       // GEMM K-tile
#define NKT (DIN / BKT)   // 8 K-tiles

typedef __attribute__((ext_vector_type(4))) float f32x4;
typedef __attribute__((ext_vector_type(8))) short s16x8;

// ---------------------------------------------------------------------------
// helpers
// ---------------------------------------------------------------------------
__device__ __forceinline__ void gl2lds16(const void* g, void* l) {
    __builtin_amdgcn_global_load_lds(
        (const __attribute__((address_space(1))) unsigned*)g,
        (__attribute__((address_space(3))) unsigned*)l, 16, 0, 0);
}

__device__ __forceinline__ unsigned short bfr(float f) {   // f32 -> bf16 RNE
    unsigned u = __float_as_uint(f);
    u += 0x7fffu + ((u >> 16) & 1u);
    return (unsigned short)(u >> 16);
}

__device__ __forceinline__ float ftanh(float x) {
    return 1.f - 2.f * __builtin_amdgcn_rcpf(1.f + __builtin_amdgcn_exp2f(x * 2.885390082f));
}

__device__ __forceinline__ float h2lo(unsigned u) {
    return (float)__builtin_bit_cast(_Float16, (unsigned short)(u & 0xffffu));
}
__device__ __forceinline__ float h2hi(unsigned u) {
    return (float)__builtin_bit_cast(_Float16, (unsigned short)(u >> 16));
}

// ---------------------------------------------------------------------------
// convert x [B][T][DIN] f32 -> x2 [(t*32+b)][DIN] bf16
// ---------------------------------------------------------------------------
__global__ __launch_bounds__(256) void convert_x(
    const float* __restrict__ x, unsigned short* __restrict__ x2)
{
    const int total4 = BB * TT * DIN / 4;
    for (int idx = blockIdx.x * 256 + threadIdx.x; idx < total4;
         idx += gridDim.x * 256) {
        int e = idx * 4;
        int b = e >> 20;
        int t = (e >> 9) & 2047;
        int i = e & 511;
        float4 v = *(const float4*)(x + (size_t)e);
        ushort4 o;
        o.x = bfr(v.x); o.y = bfr(v.y); o.z = bfr(v.z); o.w = bfr(v.w);
        *(ushort4*)(x2 + ((size_t)((t << 5) | b) << 9) + i) = o;
    }
}

// ---------------------------------------------------------------------------
// convert W: W2 row c (pair-planar): p = c>>10, d = (c&1023)>>1, q = c&1,
// gate k = 2p+q, original W row o = k*512 + d. bias permuted likewise.
// ---------------------------------------------------------------------------
__global__ __launch_bounds__(128) void convert_w(
    const float* __restrict__ W, const float* __restrict__ bias,
    unsigned short* __restrict__ W2, float* __restrict__ bias2)
{
    int c = blockIdx.x;            // 0..3071
    int p = c >> 10, d = (c & 1023) >> 1, q = c & 1;
    int o = ((2 * p + q) << 9) + d;
    const float* src = W + (size_t)o * DIN;
    unsigned short* dst = W2 + (size_t)c * DIN;
    int i = threadIdx.x * 4;
    float4 v = *(const float4*)(src + i);
    ushort4 u;
    u.x = bfr(v.x); u.y = bfr(v.y); u.z = bfr(v.z); u.w = bfr(v.w);
    *(ushort4*)(dst + i) = u;
    if (threadIdx.x == 0) bias2[c] = bias[o];
}

// ---------------------------------------------------------------------------
// 256x256 8-wave MFMA GEMM, BK=64, dbuf LDS, T2 swizzle (pre-swizzled global
// source + swizzled ds_read), counted vmcnt(8), 2 barriers per K-tile.
// Register blocking: all 8 B-frags held per K-tile (read once), A streamed
// 2 reads per M-phase => 24 ds_read_b128 / thread / K-tile (no redundancy).
// Epilogue: bias + gate activation (lane-parity select), f16 store,
// fully contiguous per row (pair-planar layout, no padding).
// ---------------------------------------------------------------------------
__global__ __launch_bounds__(512, 2) void gemm_proj8(
    const unsigned short* __restrict__ x2,    // [T*32][512] bf16
    const unsigned short* __restrict__ W2,    // [3072][512] bf16 (permuted)
    const float* __restrict__ bias2,          // [3072] (permuted)
    _Float16* __restrict__ proj,              // [Mc][PW]
    int t0)
{
    __shared__ unsigned short lds[4 * 256 * 64];   // 128 KB: A0,B0,A1,B1
    unsigned short* const A0 = lds;
    unsigned short* const B0 = lds + 16384;
    unsigned short* const A1 = lds + 32768;
    unsigned short* const B1 = lds + 49152;

    const int tid  = threadIdx.x;
    const int bx   = blockIdx.x % (NN / BNT);   // 12 col tiles
    const int by   = blockIdx.x / (NN / BNT);
    const int row0 = by * BMT;
    const int col0 = bx * BNT;
    const size_t growA = (size_t)t0 * BB + row0;

    const int lane = tid & 63;
    const int wv   = tid >> 6;       // 0..7
    const int wm   = wv >> 2;        // 0..1  (M half)
    const int wn   = wv & 3;         // 0..3  (N quarter)
    const int lr   = lane & 15;
    const int lq   = lane >> 4;

    // staging: 8 gl2lds16 per thread per K-tile; global src pre-swizzled,
    // LDS dest linear (base + lane*16 within each wave) per m104/m173.
    auto stage = [&](unsigned short* Ab, unsigned short* Bb, int kt) {
        const int k0 = kt * BKT;
        #pragma unroll
        for (int a = 0; a < 4; ++a) {
            int cid = a * 512 + tid;          // 16B-chunk id, 0..2047
            int rt  = cid >> 3;
            int cp  = cid & 7;
            int cl  = cp ^ (rt & 7);
            gl2lds16(x2 + (growA + rt) * DIN + k0 + cl * 8, Ab + rt * 64 + cp * 8);
        }
        #pragma unroll
        for (int a = 0; a < 4; ++a) {
            int cid = a * 512 + tid;
            int rt  = cid >> 3;
            int cp  = cid & 7;
            int cl  = cp ^ (rt & 7);
            gl2lds16(W2 + (size_t)(col0 + rt) * DIN + k0 + cl * 8, Bb + rt * 64 + cp * 8);
        }
    };

    f32x4 acc[8][4] = {};

    stage(A0, B0, 0);
    stage(A1, B1, 1);
    asm volatile("s_waitcnt vmcnt(8)" ::: "memory");   // tile 0 landed
    __builtin_amdgcn_s_barrier();

    #pragma unroll
    for (int kt = 0; kt < NKT; ++kt) {
        const unsigned short* Ab = (kt & 1) ? A1 : A0;
        const unsigned short* Bb = (kt & 1) ? B1 : B0;

        // read all 8 B-frags once (held in regs across the K-tile)
        s16x8 bv[4][2];
        #pragma unroll
        for (int j = 0; j < 4; ++j) {
            int col = wn * 64 + j * 16 + lr;
            #pragma unroll
            for (int x = 0; x < 2; ++x) {
                int cp = (x * 4 + lq) ^ (col & 7);
                bv[j][x] = *(const s16x8*)(Bb + col * 64 + cp * 8);
            }
        }
        // stream A: 2 reads per M-phase, 8 MFMA per phase
        #pragma unroll
        for (int m = 0; m < 8; ++m) {
            int row = wm * 128 + m * 16 + lr;
            s16x8 av0, av1;
            {
                int cp0 = (0 * 4 + lq) ^ (row & 7);
                int cp1 = (1 * 4 + lq) ^ (row & 7);
                av0 = *(const s16x8*)(Ab + row * 64 + cp0 * 8);
                av1 = *(const s16x8*)(Ab + row * 64 + cp1 * 8);
            }
            __builtin_amdgcn_s_setprio(1);
            #pragma unroll
            for (int j = 0; j < 4; ++j) {
                acc[m][j] = __builtin_amdgcn_mfma_f32_16x16x32_bf16(
                    av0, bv[j][0], acc[m][j], 0, 0, 0);
                acc[m][j] = __builtin_amdgcn_mfma_f32_16x16x32_bf16(
                    av1, bv[j][1], acc[m][j], 0, 0, 0);
            }
            __builtin_amdgcn_s_setprio(0);
        }

        __builtin_amdgcn_s_barrier();           // all waves done reading buf
        if (kt + 2 < NKT) {
            stage((kt & 1) ? A1 : A0, (kt & 1) ? B1 : B0, kt + 2);
            asm volatile("s_waitcnt vmcnt(8)" ::: "memory");  // kt+1 landed
        } else if (kt + 1 < NKT) {
            asm volatile("s_waitcnt vmcnt(0)" ::: "memory");
        }
        if (kt + 1 < NKT) __builtin_amdgcn_s_barrier();
    }

    // ---- epilogue: bias + per-gate activation + contiguous f16 store ----
    #pragma unroll
    for (int j = 0; j < 4; ++j) {
        int col = col0 + wn * 64 + j * 16 + lr;   // pair-planar col
        int p   = col >> 10;
        int q   = col & 1;
        int k   = 2 * p + q;
        float bc = bias2[col];
        const bool  isT = (k == 2);
        const bool  isI = (k == 5);
        const float m   = isT ? 2.885390082f : -1.442695041f;
        #pragma unroll
        for (int i = 0; i < 8; ++i) {
            int rbase = row0 + wm * 128 + i * 16 + lq * 4;
            #pragma unroll
            for (int r = 0; r < 4; ++r) {
                float z  = acc[i][j][r] + bc;
                float e  = __builtin_amdgcn_exp2f(z * m);
                float rr = __builtin_amdgcn_rcpf(1.f + e);
                float v  = isT ? (1.f - 2.f * rr) : rr;
                if (isI) v = z;
                proj[(size_t)(rbase + r) * PW + col] = (_Float16)v;
            }
        }
    }
}

// ---------------------------------------------------------------------------
// Scan: one thread per (b,d). 3 coalesced dword loads/step (pair planes):
//   plane0: (sig z0, sig z1)  plane1: (tanh z2, sig z3)  plane2: (sig z4, z5)
// PF=16 register prefetch.  s = a0*s + a1*t2 ; h = a3*h + a4*tanh(z5 + s)
// ---------------------------------------------------------------------------
__global__ __launch_bounds__(64) void scan_chunk(
    const _Float16* __restrict__ proj,   // [Tc*32][PW]
    const float* __restrict__ h0, const float* __restrict__ s0,
    float* __restrict__ outH, float* __restrict__ outS,
    int t0, int Tc)
{
    const int gid = blockIdx.x * 64 + threadIdx.x;   // 0..16383
    const int b   = gid >> 9;
    const int d   = gid & 511;

    float h, s;
    if (t0 == 0) { h = h0[gid]; s = s0[gid]; }
    else {
        h = outH[((size_t)b * TT + (t0 - 1)) * DD + d];
        s = outS[gid];
    }

    // dword view: row stride = 32*PW/2 uints per step; plane stride = 512
    const unsigned* pu = (const unsigned*)(proj + (size_t)b * PW + d * 2);
    const size_t tstr = (size_t)BB * PW / 2;   // 49152 uints per step
    float* oH = outH + ((size_t)b * TT + t0) * DD + d;

    unsigned bufA[PF][3], bufB[PF][3];
    #pragma unroll
    for (int u = 0; u < PF; ++u)
        #pragma unroll
        for (int p = 0; p < 3; ++p)
            bufA[u][p] = pu[(size_t)u * tstr + p * 512];

    for (int tb = 0; tb < Tc; tb += 2 * PF) {
        #pragma unroll
        for (int u = 0; u < PF; ++u) {
            int t = tb + PF + u; if (t > Tc - 1) t = Tc - 1;
            #pragma unroll
            for (int p = 0; p < 3; ++p)
                bufB[u][p] = pu[(size_t)t * tstr + p * 512];
        }
        #pragma unroll
        for (int u = 0; u < PF; ++u) {
            float a0 = h2lo(bufA[u][0]), a1 = h2hi(bufA[u][0]);
            float t2 = h2lo(bufA[u][1]), a3 = h2hi(bufA[u][1]);
            float a4 = h2lo(bufA[u][2]), z5 = h2hi(bufA[u][2]);
            s = __builtin_fmaf(a0, s, a1 * t2);
            h = __builtin_fmaf(a3, h, a4 * ftanh(z5 + s));
            oH[(size_t)(tb + u) * DD] = h;
        }
        #pragma unroll
        for (int u = 0; u < PF; ++u) {
            int t = tb + 2 * PF + u; if (t > Tc - 1) t = Tc - 1;
            #pragma unroll
            for (int p = 0; p < 3; ++p)
                bufA[u][p] = pu[(size_t)t * tstr + p * 512];
        }
        #pragma unroll
        for (int u = 0; u < PF; ++u) {
            float a0 = h2lo(bufB[u][0]), a1 = h2hi(bufB[u][0]);
            float t2 = h2lo(bufB[u][1]), a3 = h2hi(bufB[u][1]);
            float a4 = h2lo(bufB[u][2]), z5 = h2hi(bufB[u][2]);
            s = __builtin_fmaf(a0, s, a1 * t2);
            h = __builtin_fmaf(a3, h, a4 * ftanh(z5 + s));
            oH[(size_t)(tb + PF + u) * DD] = h;
        }
    }

    outS[gid] = s;
}

// ---------------------------------------------------------------------------
extern "C" void kernel_launch(void* const* d_in, const int* in_sizes, int n_in,
                              void* d_out, int out_size, void* d_ws, size_t ws_size,
                              hipStream_t stream) {
    const float* x    = (const float*)d_in[0];
    const float* h0   = (const float*)d_in[1];
    const float* s0   = (const float*)d_in[2];
    const float* W    = (const float*)d_in[3];
    const float* bias = (const float*)d_in[4];

    float* outH = (float*)d_out;
    float* outS = outH + (size_t)BB * TT * DD;

    char* ws = (char*)d_ws;
    const size_t x2_bytes = (size_t)BB * TT * DIN * 2;       // 64 MB
    const size_t w2_bytes = (size_t)NN * DIN * 2;            // 3 MB
    const size_t b2_bytes = (size_t)NN * 4;
    unsigned short* x2    = (unsigned short*)ws;
    unsigned short* W2    = (unsigned short*)(ws + x2_bytes);
    float*          bias2 = (float*)(ws + x2_bytes + w2_bytes);
    _Float16*       proj  = (_Float16*)(ws + x2_bytes + w2_bytes + b2_bytes);

    const size_t fixed = x2_bytes + w2_bytes + b2_bytes;
    const size_t per_t = (size_t)BB * PW * 2;                // 192 KB / step
    size_t avail = ws_size > fixed ? ws_size - fixed : 0;
    int TcMax = (int)(avail / per_t);
    if (TcMax > 512) TcMax = 512;   // keep proj chunk L3-resident
    TcMax &= ~31;                   // multiple of 32 (scan 2*PF, M tile 256)
    if (TcMax < 32) TcMax = 32;

    convert_x<<<2048, 256, 0, stream>>>(x, x2);
    convert_w<<<NN, 128, 0, stream>>>(W, bias, W2, bias2);

    for (int t0 = 0; t0 < TT; t0 += TcMax) {
        int Tc = TT - t0;
        if (Tc > TcMax) Tc = TcMax;
        int nblk = (NN / BNT) * (Tc * BB / BMT);
        gemm_proj8<<<nblk, 512, 0, stream>>>(x2, W2, bias2, proj, t0);
        scan_chunk<<<(BB * DD) / 64, 64, 0, stream>>>(proj, h0, s0, outH, outS, t0, Tc);
    }
}